// Round 2
// baseline (1351.089 us; speedup 1.0000x reference)
//
#include <hip/hip_runtime.h>
#include <hip/hip_bf16.h>

#define D 128

typedef unsigned int u32;
typedef unsigned short ushort_t;

__device__ __forceinline__ float bf2f(ushort_t u){ return __uint_as_float(((u32)u)<<16); }
__device__ __forceinline__ ushort_t f2bf(float f){
  u32 x = __float_as_uint(f);
  return (ushort_t)((x + 0x7fffu + ((x>>16)&1u)) >> 16);
}
// packed dword = two consecutive bf16 elements (lo = even col, hi = odd col)
__device__ __forceinline__ float2 bfp2(u32 w){
  float2 r; r.x = __uint_as_float(w<<16); r.y = __uint_as_float(w & 0xffff0000u); return r;
}
__device__ __forceinline__ u32 packbf(float a, float b){
  return (u32)f2bf(a) | ((u32)f2bf(b)<<16);
}
__device__ __forceinline__ float sigm(float x){ return 1.0f/(1.0f+__expf(-x)); }
__device__ __forceinline__ float ftanh(float x){
  float e = __expf(-2.0f*fabsf(x));
  float t = (1.0f-e)/(1.0f+e);
  return copysignf(t,x);
}

// ---------------- dtype probe ----------------
// Examine 512 words of rela_embed (~N(0,0.05^2)). If data is bf16-packed, the
// LOW ushort of each word is a bf16 whose exponent field lies in [100,126]
// (~always). If data is f32, the low 16 bits are uniform mantissa bits ->
// band hit-rate ~10.5%. flag=1 means f32.
__global__ void detect_kernel(const u32* __restrict__ words, int* flag){
  int t = threadIdx.x;
  int cnt = 0;
  for (int i = t; i < 512; i += 64){
    u32 w = words[i];
    u32 e = (w >> 7) & 0xFFu;
    if (e >= 100u && e <= 126u) cnt++;
  }
  #pragma unroll
  for (int off = 32; off > 0; off >>= 1) cnt += __shfl_xor(cnt, off);
  if (t == 0) *flag = (cnt < 256) ? 1 : 0;
}

// ---------------- canonicalize all float inputs to bf16 ----------------
struct CvtArgs { const void* src[17]; ushort_t* dst[17]; int n[17]; };

__global__ __launch_bounds__(256) void convert_kernel(CvtArgs a, const int* __restrict__ flag){
  int isf = *flag;
  int gid = blockIdx.x*blockDim.x + threadIdx.x;
  int gs  = gridDim.x*blockDim.x;
  for (int s = 0; s < 17; s++){
    int n = a.n[s];
    ushort_t* dst = a.dst[s];
    if (isf){
      const float* src = (const float*)a.src[s];
      for (int j = gid; j < n; j += gs) dst[j] = f2bf(src[j]);
    } else {
      const ushort_t* src = (const ushort_t*)a.src[s];
      for (int j = gid; j < n; j += gs) dst[j] = src[j];
    }
  }
}

// ---------------- init: zero accumulators ----------------
__global__ void init_kernel(float* agg, float* sum_exp, int* last_edge, int N){
  int i = blockIdx.x*blockDim.x + threadIdx.x;
  int stride = gridDim.x*blockDim.x;
  for (int j=i; j<N*D; j+=stride) agg[j]=0.f;
  for (int j=i; j<N;   j+=stride){ sum_exp[j]=0.f; last_edge[j]=-1; }
}

// ---------------- per-rel and per-query tables ----------------
__global__ void table_kernel(const ushort_t* __restrict__ rela,
  const ushort_t* __restrict__ Wz, const ushort_t* __restrict__ Wr, const ushort_t* __restrict__ Wh,
  const ushort_t* __restrict__ Wqr,
  const ushort_t* __restrict__ bz, const ushort_t* __restrict__ br, const ushort_t* __restrict__ bh,
  const ushort_t* __restrict__ bqr,
  const int* __restrict__ q_rel,
  ushort_t* hq_tab, ushort_t* Az, ushort_t* Ar, ushort_t* Ah,
  ushort_t* Bz, ushort_t* Br, ushort_t* Bh, ushort_t* Ca, int NRE, int NQ)
{
  __shared__ float hrow[D];
  int d = threadIdx.x;
  int b = blockIdx.x;
  if (b < NRE) {
    const ushort_t* row = rela + (size_t)b*D;
    hrow[d] = bf2f(row[d]);
    __syncthreads();
    float az=0.f, ar=0.f, ah=0.f;
    for (int k=0;k<D;k++){
      float h = hrow[k];
      az += h*bf2f(Wz[k*D+d]);
      ar += h*bf2f(Wr[k*D+d]);
      ah += h*bf2f(Wh[k*D+d]);
    }
    Az[b*D+d]=f2bf(az); Ar[b*D+d]=f2bf(ar); Ah[b*D+d]=f2bf(ah);
  } else {
    int q = b - NRE; if (q >= NQ) return;
    int rq = q_rel[q];
    const ushort_t* row = rela + (size_t)rq*D;
    hrow[d] = bf2f(row[d]);
    hq_tab[q*D+d] = row[d];
    __syncthreads();
    float vz=bf2f(bz[d]), vr=bf2f(br[d]), vh=bf2f(bh[d]), vc=bf2f(bqr[d]);
    for (int k=0;k<D;k++){
      float h = hrow[k];
      vz += h*bf2f(Wz[(D+k)*D+d]);
      vr += h*bf2f(Wr[(D+k)*D+d]);
      vh += h*bf2f(Wh[(D+k)*D+d]);
      vc += h*bf2f(Wqr[k*D+d]);
    }
    Bz[q*D+d]=f2bf(vz); Br[q*D+d]=f2bf(vr); Bh[q*D+d]=f2bf(vh); Ca[q*D+d]=f2bf(vc);
  }
}

// ---------------- HU = hidden @ Uz, hidden @ Ur ----------------
__global__ __launch_bounds__(256) void hu_kernel(const ushort_t* __restrict__ hidden,
  const ushort_t* __restrict__ Uz, const ushort_t* __restrict__ Ur,
  ushort_t* __restrict__ HUz, ushort_t* __restrict__ HUr, int N)
{
  int l = threadIdx.x & 63;
  int gw = (int)((blockIdx.x * blockDim.x + threadIdx.x) >> 6);
  int nw = (int)((gridDim.x * blockDim.x) >> 6);
  int c0 = 2*l;
  for (int n = gw; n < N; n += nw) {
    float2 h = bfp2(*(const u32*)(hidden + (size_t)n*D + c0));
    float az0=0.f,az1=0.f,ar0=0.f,ar1=0.f;
    #pragma unroll 4
    for (int kp=0; kp<64; kp++) {
      float hx = __shfl(h.x, kp);
      float hy = __shfl(h.y, kp);
      float2 uz0 = bfp2(*(const u32*)(Uz + (2*kp)*D + c0));
      float2 uz1 = bfp2(*(const u32*)(Uz + (2*kp+1)*D + c0));
      float2 ur0 = bfp2(*(const u32*)(Ur + (2*kp)*D + c0));
      float2 ur1 = bfp2(*(const u32*)(Ur + (2*kp+1)*D + c0));
      az0 += hx*uz0.x + hy*uz1.x;
      az1 += hx*uz0.y + hy*uz1.y;
      ar0 += hx*ur0.x + hy*ur1.x;
      ar1 += hx*ur0.y + hy*ur1.y;
    }
    *(u32*)(HUz + (size_t)n*D + c0) = packbf(az0, az1);
    *(u32*)(HUr + (size_t)n*D + c0) = packbf(ar0, ar1);
  }
}

// ---------------- main per-edge kernel ----------------
__global__ __launch_bounds__(256) void edge_kernel(
  const int* __restrict__ edges,
  const ushort_t* __restrict__ hidden,
  const ushort_t* __restrict__ HUz, const ushort_t* __restrict__ HUr,
  const ushort_t* __restrict__ Az, const ushort_t* __restrict__ Ar, const ushort_t* __restrict__ Ah,
  const ushort_t* __restrict__ Bz, const ushort_t* __restrict__ Br, const ushort_t* __restrict__ Bh,
  const ushort_t* __restrict__ Ca,
  const ushort_t* __restrict__ Uh, const ushort_t* __restrict__ Ws,
  const ushort_t* __restrict__ w_alpha, const ushort_t* __restrict__ b_alpha,
  float* __restrict__ agg, float* __restrict__ sum_exp, int* __restrict__ last_edge,
  int E)
{
  __shared__ ushort_t UhL[D*D];       // 32KB bf16
  __shared__ float vbuf[4][D][4];     // 8KB (wave-private: [wave][k][edge])
  __shared__ float mbuf[4][D][4];     // 8KB
  int tid = threadIdx.x;
  for (int i = tid*8; i < D*D; i += 256*8)
    *(uint4*)(UhL + i) = *(const uint4*)(Uh + i);
  __syncthreads();

  int w = tid >> 6, l = tid & 63;
  int c0 = 2*l, c1 = 2*l+1;
  float wal0 = bf2f(w_alpha[c0]), wal1 = bf2f(w_alpha[c1]);
  float bal  = bf2f(b_alpha[0]);
  int nIter = (E + 15) >> 4;

  for (int it = blockIdx.x; it < nIter; it += gridDim.x) {
    int ebase = it*16 + w*4;
    float z0[4],z1[4],hs0[4],hs1[4],ac0[4],ac1[4];
    int obj[4], ridx[4];
    #pragma unroll
    for (int e=0;e<4;e++){
      int eg = ebase + e; if (eg >= E) eg = E-1;
      ridx[e] = edges[(size_t)eg*6+0];
      int rel = edges[(size_t)eg*6+2];
      int sub = edges[(size_t)eg*6+4];
      obj[e]  = edges[(size_t)eg*6+5];
      float2 vaz = bfp2(*(const u32*)(Az + (size_t)rel*D + c0));
      float2 vbz = bfp2(*(const u32*)(Bz + (size_t)ridx[e]*D + c0));
      float2 vhz = bfp2(*(const u32*)(HUz + (size_t)sub*D + c0));
      float2 var2 = bfp2(*(const u32*)(Ar + (size_t)rel*D + c0));
      float2 vbr = bfp2(*(const u32*)(Br + (size_t)ridx[e]*D + c0));
      float2 vhr = bfp2(*(const u32*)(HUr + (size_t)sub*D + c0));
      float2 hs  = bfp2(*(const u32*)(hidden + (size_t)sub*D + c0));
      float zz0 = sigm(vaz.x+vbz.x+vhz.x);
      float zz1 = sigm(vaz.y+vbz.y+vhz.y);
      float rr0 = sigm(var2.x+vbr.x+vhr.x);
      float rr1 = sigm(var2.y+vbr.y+vhr.y);
      vbuf[w][c0][e] = rr0*hs.x;
      vbuf[w][c1][e] = rr1*hs.y;
      z0[e]=zz0; z1[e]=zz1; hs0[e]=hs.x; hs1[e]=hs.y;
      float2 vah = bfp2(*(const u32*)(Ah + (size_t)rel*D + c0));
      float2 vbh = bfp2(*(const u32*)(Bh + (size_t)ridx[e]*D + c0));
      ac0[e]=vah.x+vbh.x; ac1[e]=vah.y+vbh.y;
    }
    // matvec 1: ac += (r*h_s) @ Uh
    #pragma unroll 4
    for (int kp=0; kp<64; kp++){
      float4 va = *(float4*)&vbuf[w][2*kp][0];
      float4 vb = *(float4*)&vbuf[w][2*kp+1][0];
      float2 u0 = bfp2(*(u32*)(UhL + (2*kp)*D + c0));
      float2 u1 = bfp2(*(u32*)(UhL + (2*kp+1)*D + c0));
      ac0[0] += va.x*u0.x + vb.x*u1.x;  ac1[0] += va.x*u0.y + vb.x*u1.y;
      ac0[1] += va.y*u0.x + vb.y*u1.x;  ac1[1] += va.y*u0.y + vb.y*u1.y;
      ac0[2] += va.z*u0.x + vb.z*u1.x;  ac1[2] += va.z*u0.y + vb.z*u1.y;
      ac0[3] += va.w*u0.x + vb.w*u1.x;  ac1[3] += va.w*u0.y + vb.w*u1.y;
    }
    float m0[4], m1[4], a20[4], a21[4];
    #pragma unroll
    for (int e=0;e<4;e++){
      float ht0 = ftanh(ac0[e]), ht1 = ftanh(ac1[e]);
      float mm0 = (1.0f - z0[e])*hs0[e] + z0[e]*ht0;
      float mm1 = (1.0f - z1[e])*hs1[e] + z1[e]*ht1;
      mbuf[w][c0][e]=mm0; mbuf[w][c1][e]=mm1;
      m0[e]=mm0; m1[e]=mm1;
      float2 ca = bfp2(*(const u32*)(Ca + (size_t)ridx[e]*D + c0));
      a20[e]=ca.x; a21[e]=ca.y;
    }
    // matvec 2: a2 += message @ Ws_attn
    #pragma unroll 4
    for (int kp=0; kp<64; kp++){
      float4 ma = *(float4*)&mbuf[w][2*kp][0];
      float4 mb = *(float4*)&mbuf[w][2*kp+1][0];
      float2 u0 = bfp2(*(const u32*)(Ws + (2*kp)*D + c0));
      float2 u1 = bfp2(*(const u32*)(Ws + (2*kp+1)*D + c0));
      a20[0] += ma.x*u0.x + mb.x*u1.x;  a21[0] += ma.x*u0.y + mb.x*u1.y;
      a20[1] += ma.y*u0.x + mb.y*u1.x;  a21[1] += ma.y*u0.y + mb.y*u1.y;
      a20[2] += ma.z*u0.x + mb.z*u1.x;  a21[2] += ma.z*u0.y + mb.z*u1.y;
      a20[3] += ma.w*u0.x + mb.w*u1.x;  a21[3] += ma.w*u0.y + mb.w*u1.y;
    }
    #pragma unroll
    for (int e=0;e<4;e++){
      float s = fmaxf(a20[e],0.f)*wal0 + fmaxf(a21[e],0.f)*wal1;
      #pragma unroll
      for (int off=32; off>0; off>>=1) s += __shfl_xor(s, off);
      float ea = __expf(s + bal);
      int eg = ebase + e;
      if (eg < E){
        float* ap = agg + (size_t)obj[e]*D;
        atomicAdd(ap + c0, ea*m0[e]);
        atomicAdd(ap + c1, ea*m1[e]);
        if (l == 0){
          atomicAdd(sum_exp + obj[e], ea);
          atomicMax(last_edge + obj[e], eg);
        }
      }
    }
  }
}

// ---------------- finalize (4-node batched, dual output format) ----------------
__global__ __launch_bounds__(256) void final_kernel(
  const float* __restrict__ agg, const float* __restrict__ sum_exp,
  const int* __restrict__ last_edge, const int* __restrict__ edges,
  const ushort_t* __restrict__ hq_tab, const ushort_t* __restrict__ Wh,
  const int* __restrict__ flag, void* __restrict__ out_base, int N)
{
  __shared__ float mb[4][D][4];
  int tid = threadIdx.x, w = tid >> 6, l = tid & 63;
  int c0 = 2*l, c1 = c0+1;
  int isf = *flag;
  float* out0f = (float*)out_base;
  float* out1f = out0f + (size_t)N*D;
  ushort_t* out0h = (ushort_t*)out_base;
  ushort_t* out1h = out0h + (size_t)N*D;
  int nIter = (N + 15) >> 4;
  for (int it = blockIdx.x; it < nIter; it += gridDim.x){
    int base = it*16 + w*4;
    int rq[4];
    #pragma unroll
    for (int e=0;e<4;e++){
      int n = base + e; if (n >= N) n = N-1;
      float se = sum_exp[n];
      float inv = (se > 0.f) ? (1.0f/se) : 0.f;
      float2 m = *(const float2*)(agg + (size_t)n*D + c0);
      mb[w][c0][e] = m.x*inv; mb[w][c1][e] = m.y*inv;
      int le = last_edge[n];
      rq[e] = (le >= 0) ? edges[(size_t)le*6] : 0;
    }
    float a0[4] = {0,0,0,0}, a1[4] = {0,0,0,0};
    #pragma unroll 4
    for (int kp=0; kp<64; kp++){
      float4 ma = *(float4*)&mb[w][2*kp][0];
      float4 mv = *(float4*)&mb[w][2*kp+1][0];
      float2 u0 = bfp2(*(const u32*)(Wh + (2*kp)*D + c0));
      float2 u1 = bfp2(*(const u32*)(Wh + (2*kp+1)*D + c0));
      a0[0] += ma.x*u0.x + mv.x*u1.x;  a1[0] += ma.x*u0.y + mv.x*u1.y;
      a0[1] += ma.y*u0.x + mv.y*u1.x;  a1[1] += ma.y*u0.y + mv.y*u1.y;
      a0[2] += ma.z*u0.x + mv.z*u1.x;  a1[2] += ma.z*u0.y + mv.z*u1.y;
      a0[3] += ma.w*u0.x + mv.w*u1.x;  a1[3] += ma.w*u0.y + mv.w*u1.y;
    }
    #pragma unroll
    for (int e=0;e<4;e++){
      int n = base + e; if (n >= N) continue;
      float r0 = fmaxf(a0[e], 0.f), r1 = fmaxf(a1[e], 0.f);
      u32 hqw = *(const u32*)(hq_tab + (size_t)rq[e]*D + c0);
      if (isf){
        float2 o0; o0.x = r0; o0.y = r1;
        *(float2*)(out0f + (size_t)n*D + c0) = o0;
        float2 hv = bfp2(hqw);
        *(float2*)(out1f + (size_t)n*D + c0) = hv;
      } else {
        *(u32*)(out0h + (size_t)n*D + c0) = packbf(r0, r1);
        *(u32*)(out1h + (size_t)n*D + c0) = hqw;
      }
    }
  }
}

extern "C" void kernel_launch(void* const* d_in, const int* in_sizes, int n_in,
                              void* d_out, int out_size, void* d_ws, size_t ws_size,
                              hipStream_t stream)
{
  const int* q_rel = (const int*)d_in[17];
  const int* edges = (const int*)d_in[18];

  int N   = in_sizes[0]/D;
  int NRE = in_sizes[1]/D;
  int NQ  = in_sizes[17];
  int E   = in_sizes[18]/6;

  char* ws = (char*)d_ws;
  size_t o = 0;
  auto alloc = [&](size_t bytes)->void*{
    void* p = ws + o; o += (bytes + 255) & ~(size_t)255; return p;
  };
  float* agg      = (float*)alloc((size_t)N*D*4);
  float* sum_exp  = (float*)alloc((size_t)N*4);
  int*   lastedge = (int*)  alloc((size_t)N*4);
  int*   flag     = (int*)  alloc(256);

  // canonical bf16 copies of the 17 float inputs
  ushort_t* canon[17];
  for (int i=0;i<17;i++) canon[i] = (ushort_t*)alloc((size_t)in_sizes[i]*2);

  ushort_t* hq_tab = (ushort_t*)alloc((size_t)NQ*D*2);
  ushort_t* Az = (ushort_t*)alloc((size_t)NRE*D*2);
  ushort_t* Ar = (ushort_t*)alloc((size_t)NRE*D*2);
  ushort_t* Ah = (ushort_t*)alloc((size_t)NRE*D*2);
  ushort_t* Bz = (ushort_t*)alloc((size_t)NQ*D*2);
  ushort_t* Br = (ushort_t*)alloc((size_t)NQ*D*2);
  ushort_t* Bh = (ushort_t*)alloc((size_t)NQ*D*2);
  ushort_t* Ca = (ushort_t*)alloc((size_t)NQ*D*2);
  ushort_t* HUz = (ushort_t*)alloc((size_t)N*D*2);
  ushort_t* HUr = (ushort_t*)alloc((size_t)N*D*2);

  CvtArgs ca;
  for (int i=0;i<17;i++){ ca.src[i]=d_in[i]; ca.dst[i]=canon[i]; ca.n[i]=in_sizes[i]; }

  const ushort_t* hidden = canon[0];
  const ushort_t* rela   = canon[1];
  const ushort_t* Wz  = canon[2];
  const ushort_t* Uz  = canon[3];
  const ushort_t* bz  = canon[4];
  const ushort_t* Wr  = canon[5];
  const ushort_t* Ur  = canon[6];
  const ushort_t* br  = canon[7];
  const ushort_t* Whh = canon[8];
  const ushort_t* Uh  = canon[9];
  const ushort_t* bh  = canon[10];
  const ushort_t* Ws  = canon[11];
  const ushort_t* Wqr = canon[12];
  const ushort_t* bqr = canon[13];
  const ushort_t* wal = canon[14];
  const ushort_t* bal = canon[15];
  const ushort_t* W_h = canon[16];

  detect_kernel<<<1, 64, 0, stream>>>((const u32*)d_in[1], flag);
  convert_kernel<<<1024, 256, 0, stream>>>(ca, flag);
  init_kernel<<<4096, 256, 0, stream>>>(agg, sum_exp, lastedge, N);
  table_kernel<<<NRE+NQ, 128, 0, stream>>>(rela, Wz, Wr, Whh, Wqr, bz, br, bh, bqr,
                                           q_rel, hq_tab, Az, Ar, Ah, Bz, Br, Bh, Ca, NRE, NQ);
  hu_kernel<<<1024, 256, 0, stream>>>(hidden, Uz, Ur, HUz, HUr, N);
  edge_kernel<<<1536, 256, 0, stream>>>(edges, hidden, HUz, HUr, Az, Ar, Ah, Bz, Br, Bh, Ca,
                                        Uh, Ws, wal, bal, agg, sum_exp, lastedge, E);
  final_kernel<<<1024, 256, 0, stream>>>(agg, sum_exp, lastedge, edges, hq_tab, W_h,
                                         flag, d_out, N);
}